// Round 6
// baseline (611.231 us; speedup 1.0000x reference)
//
#include <hip/hip_runtime.h>
#include <hip/hip_cooperative_groups.h>
#include <math.h>

namespace cg = cooperative_groups;

#define NN 20000
#define NE 640000
#define D  128
#define NSLICE 2500        // NN / 8 XCDs
#define NTHR 256
#define NTILES 625         // NN / 32 rows per GEMM tile (exact)

typedef __attribute__((ext_vector_type(8))) short short8;
typedef __attribute__((ext_vector_type(4))) float floatx4;

static __device__ __forceinline__ unsigned short f2bf(float f) {
    union { float f; unsigned int u; } v; v.f = f;
    unsigned int u = v.u;
    u += 0x7fff + ((u >> 16) & 1);   // round-to-nearest-even
    return (unsigned short)(u >> 16);
}
static __device__ __forceinline__ unsigned int pack2bf(float a, float b) {
    return (unsigned int)f2bf(a) | ((unsigned int)f2bf(b) << 16);
}
static __device__ __forceinline__ float bf_lo(unsigned int u) {
    union { unsigned int i; float f; } v; v.i = u << 16; return v.f;
}
static __device__ __forceinline__ float bf_hi(unsigned int u) {
    union { unsigned int i; float f; } v; v.i = u & 0xffff0000u; return v.f;
}
static __device__ __forceinline__ float sigm(float x) { return 1.f / (1.f + __expf(-x)); }
static __device__ __forceinline__ float tanhx(float x) { return 1.f - 2.f / (__expf(2.f * x) + 1.f); }

// Phases (gridDim-agnostic; grid multiple of 8 blocks):
// P0 zero counts/tileCtr | P1 prep (degree+pack+Wt) | P2 scan | P3 fill CSR
// P4 weighted-mean aggregate | P5 GEMM+LSTM (dynamic M-tiles, register-only)
// Cooperative path runs pLo=0..pHi=5 with grid.sync between phases; fallback
// path launches one phase per plain kernel launch (pLo==pHi, no grid.sync).
__global__ void __launch_bounds__(NTHR, 2)
fused_kernel(const int* __restrict__ srcE, const int* __restrict__ dstE,
             const float* __restrict__ ew,
             const float4* __restrict__ X4, const float4* __restrict__ H4,
             const float* __restrict__ Wx_l, const float* __restrict__ Wx_r,
             const float* __restrict__ Wh_l, const float* __restrict__ Wh_r,
             const float* __restrict__ bx, const float* __restrict__ bh,
             const float* __restrict__ bg, const float* __restrict__ wc,
             const float* __restrict__ C, float* __restrict__ out,
             int* __restrict__ counts, int* __restrict__ cursor,
             unsigned int* __restrict__ s_p,
             unsigned short* __restrict__ XH, unsigned short* __restrict__ AGG,
             unsigned short* __restrict__ Wt, float* __restrict__ bias,
             int* __restrict__ tileCtr, int pLo, int pHi)
{
    __shared__ int part[NTHR];
    __shared__ int tileShared;

    const int tid = threadIdx.x;
    const int b = blockIdx.x;
    const int G = gridDim.x;
    const int gt = b * NTHR + tid;
    const int GT = G * NTHR;

    for (int ph = pLo; ph <= pHi; ++ph) {
        switch (ph) {
        case 0: {
            for (int t = gt; t < NN; t += GT) counts[t] = 0;
            if (gt == 0) *tileCtr = 0;
        } break;

        case 1: {
            for (int t = gt; t < NE; t += GT) {
                atomicAdd(&counts[dstE[t]], 1);
                float4 x = X4[t];
                float4 h = H4[t];
                int n = t >> 5, q = t & 31;
                unsigned int* row = (unsigned int*)XH + (size_t)n * 128;
                row[2 * q]          = pack2bf(x.x, x.y);
                row[2 * q + 1]      = pack2bf(x.z, x.w);
                row[64 + 2 * q]     = pack2bf(h.x, h.y);
                row[64 + 2 * q + 1] = pack2bf(h.z, h.w);
                if (t < 512 * 512) {
                    int j = t >> 9, k = t & 511, g = j >> 7, o = j & 127;
                    float w;
                    if (k < 128)      w = Wx_l[g * 16384 + k * 128 + o];
                    else if (k < 256) w = Wx_r[g * 16384 + (k - 128) * 128 + o];
                    else if (k < 384) w = Wh_l[g * 16384 + (k - 256) * 128 + o];
                    else              w = Wh_r[g * 16384 + (k - 384) * 128 + o];
                    Wt[j * 512 + k] = f2bf(w);
                    if (k == 0) bias[j] = bx[g * 128 + o] + bh[g * 128 + o] + bg[g * 128 + o];
                }
            }
        } break;

        case 2: {
            if (b == 0) {
                const int PER = 79;   // 79*256 = 20224 >= NN
                int base = tid * PER;
                int local = 0;
                for (int i = 0; i < PER; ++i) {
                    int idx = base + i;
                    if (idx < NN) local += counts[idx];
                }
                part[tid] = local;
                __syncthreads();
                for (int off = 1; off < NTHR; off <<= 1) {
                    int v = (tid >= off) ? part[tid - off] : 0;
                    __syncthreads();
                    part[tid] += v;
                    __syncthreads();
                }
                int run = part[tid] - local;
                for (int i = 0; i < PER; ++i) {
                    int idx = base + i;
                    if (idx < NN) { int cv = counts[idx]; cursor[idx] = run; run += cv; }
                }
            }
        } break;

        case 3: {
            // XCD-sliced CSR fill: block handles dst-slice s over an edge chunk.
            int s = b & 7, chunk = b >> 3;
            int nch = G >> 3;
            int per = (NE + nch - 1) / nch;
            int lo = s * NSLICE, hi = lo + NSLICE;
            int e0 = chunk * per;
            int e1 = (e0 + per < NE) ? e0 + per : NE;
            for (int e = e0 + tid; e < e1; e += NTHR) {
                int d = dstE[e];
                if (d >= lo && d < hi) {
                    int p = atomicAdd(&cursor[d], 1);
                    s_p[p] = (unsigned int)srcE[e] | ((unsigned int)f2bf(ew[e]) << 16);
                }
            }
        } break;

        case 4: {
            int wv = tid >> 6, lane = tid & 63;
            int s = b & 7;
            int wi = (b >> 3) * 4 + wv;
            int wstride = (G >> 3) * 4;
            const uint2* XH64 = (const uint2*)XH;
            uint2* AGG64 = (uint2*)AGG;
            for (int n = s * NSLICE + wi; n < (s + 1) * NSLICE; n += wstride) {
                int s1 = cursor[n];
                int s0 = (n > 0) ? cursor[n - 1] : 0;
                float a0 = 0.f, a1 = 0.f, a2 = 0.f, a3 = 0.f;
                int i = s0;
                for (; i + 16 <= s1; i += 16) {
                    unsigned int e[16];
                    uint2 u[16];
#pragma unroll
                    for (int k = 0; k < 16; ++k) e[k] = s_p[i + k];
#pragma unroll
                    for (int k = 0; k < 16; ++k) u[k] = XH64[(size_t)(e[k] & 0xffff) * 64 + lane];
#pragma unroll
                    for (int k = 0; k < 16; ++k) {
                        float w = __int_as_float(e[k] & 0xffff0000u);
                        a0 += bf_lo(u[k].x) * w;
                        a1 += bf_hi(u[k].x) * w;
                        a2 += bf_lo(u[k].y) * w;
                        a3 += bf_hi(u[k].y) * w;
                    }
                }
                for (; i + 4 <= s1; i += 4) {
                    unsigned int e[4];
                    uint2 u[4];
#pragma unroll
                    for (int k = 0; k < 4; ++k) e[k] = s_p[i + k];
#pragma unroll
                    for (int k = 0; k < 4; ++k) u[k] = XH64[(size_t)(e[k] & 0xffff) * 64 + lane];
#pragma unroll
                    for (int k = 0; k < 4; ++k) {
                        float w = __int_as_float(e[k] & 0xffff0000u);
                        a0 += bf_lo(u[k].x) * w;
                        a1 += bf_hi(u[k].x) * w;
                        a2 += bf_lo(u[k].y) * w;
                        a3 += bf_hi(u[k].y) * w;
                    }
                }
                for (; i < s1; ++i) {
                    unsigned int e = s_p[i];
                    float w = __int_as_float(e & 0xffff0000u);
                    uint2 u = XH64[(size_t)(e & 0xffff) * 64 + lane];
                    a0 += bf_lo(u.x) * w;
                    a1 += bf_hi(u.x) * w;
                    a2 += bf_lo(u.y) * w;
                    a3 += bf_hi(u.y) * w;
                }
                float inv = (s1 > s0) ? 1.0f / (float)(s1 - s0) : 1.0f;
                uint2 r;
                r.x = pack2bf(a0 * inv, a1 * inv);
                r.y = pack2bf(a2 * inv, a3 * inv);
                AGG64[(size_t)n * 64 + lane] = r;
            }
        } break;

        case 5: {
            // Dynamic 32-row tiles; wave wv owns in-gate cols [wv*32,wv*32+32)
            // across all 4 gates -> in-register LSTM epilogue. B from L2-resident Wt.
            int wv = tid >> 6, lane = tid & 63;
            int lm = lane & 15, lq = lane >> 4;

            float bG[4][2], wP[3][2];
#pragma unroll
            for (int nt = 0; nt < 2; ++nt) {
                int cg0 = (wv << 5) + (nt << 4) + lm;
#pragma unroll
                for (int g = 0; g < 4; ++g) bG[g][nt] = bias[(g << 7) + cg0];
#pragma unroll
                for (int j = 0; j < 3; ++j) wP[j][nt] = wc[j * 128 + cg0];
            }

            const unsigned short* brow = Wt + (size_t)((wv << 5) + lm) * 512 + lq * 8;

            for (;;) {
                if (tid == 0) tileShared = atomicAdd(tileCtr, 1);
                __syncthreads();
                int tile = tileShared;
                __syncthreads();
                if (tile >= NTILES) break;
                int m0 = tile * 32;

                floatx4 acc[2][4][2];
#pragma unroll
                for (int mt = 0; mt < 2; ++mt)
#pragma unroll
                    for (int g = 0; g < 4; ++g)
#pragma unroll
                        for (int nt = 0; nt < 2; ++nt) acc[mt][g][nt] = (floatx4)(0.f);

                short8 ca0, ca1, cb[4][2], na0, na1, nb[4][2];
                {
                    const unsigned short* ar = AGG + (size_t)(m0 + lm) * 256 + lq * 8;
                    ca0 = *(const short8*)ar;
                    ca1 = *(const short8*)(ar + 16 * 256);
#pragma unroll
                    for (int g = 0; g < 4; ++g)
#pragma unroll
                        for (int nt = 0; nt < 2; ++nt)
                            cb[g][nt] = *(const short8*)(brow + (size_t)((g << 7) + (nt << 4)) * 512);
                }

                for (int it = 0; it < 16; ++it) {
                    if (it < 15) {
                        int kb = (it + 1) * 32;
                        const unsigned short* ab = (kb & 128) ? XH : AGG;
                        int aoff = (kb & 127) | ((kb & 256) >> 1);
                        const unsigned short* arn = ab + (size_t)(m0 + lm) * 256 + aoff + lq * 8;
                        na0 = *(const short8*)arn;
                        na1 = *(const short8*)(arn + 16 * 256);
                        const unsigned short* brn = brow + kb;
#pragma unroll
                        for (int g = 0; g < 4; ++g)
#pragma unroll
                            for (int nt = 0; nt < 2; ++nt)
                                nb[g][nt] = *(const short8*)(brn + (size_t)((g << 7) + (nt << 4)) * 512);
                    }
#pragma unroll
                    for (int g = 0; g < 4; ++g)
#pragma unroll
                        for (int nt = 0; nt < 2; ++nt) {
                            acc[0][g][nt] = __builtin_amdgcn_mfma_f32_16x16x32_bf16(ca0, cb[g][nt], acc[0][g][nt], 0, 0, 0);
                            acc[1][g][nt] = __builtin_amdgcn_mfma_f32_16x16x32_bf16(ca1, cb[g][nt], acc[1][g][nt], 0, 0, 0);
                        }
                    ca0 = na0; ca1 = na1;
#pragma unroll
                    for (int g = 0; g < 4; ++g)
#pragma unroll
                        for (int nt = 0; nt < 2; ++nt) cb[g][nt] = nb[g][nt];
                }

#pragma unroll
                for (int mt = 0; mt < 2; ++mt)
#pragma unroll
                    for (int r = 0; r < 4; ++r) {
                        int row = m0 + mt * 16 + lq * 4 + r;
#pragma unroll
                        for (int nt = 0; nt < 2; ++nt) {
                            int cg0 = (wv << 5) + (nt << 4) + lm;
                            float c = C[(size_t)row * D + cg0];
                            float pi = acc[mt][0][nt][r] + bG[0][nt] + wP[0][nt] * c;
                            float pf = acc[mt][1][nt][r] + bG[1][nt] + wP[1][nt] * c;
                            float pt = acc[mt][2][nt][r] + bG[2][nt];
                            float po = acc[mt][3][nt][r] + bG[3][nt];
                            float I = sigm(pi);
                            float F = sigm(pf);
                            float T = tanhx(pt);
                            float cn = F * c + I * T;
                            float O = sigm(po + wP[2][nt] * cn);
                            out[(size_t)row * D + cg0] = O * tanhx(cn);
                            out[(size_t)NN * D + (size_t)row * D + cg0] = cn;
                        }
                    }
            }
        } break;
        }
        if (ph < pHi) cg::this_grid().sync();
    }
}

extern "C" void kernel_launch(void* const* d_in, const int* in_sizes, int n_in,
                              void* d_out, int out_size, void* d_ws, size_t ws_size,
                              hipStream_t stream) {
    const int* srcE = (const int*)d_in[1];
    const int* dstE = ((const int*)d_in[1]) + NE;
    const float* ewp = (const float*)d_in[2];
    const float4* X4 = (const float4*)d_in[0];
    const float4* H4 = (const float4*)d_in[3];
    const float* Cp  = (const float*)d_in[4];
    const float* Wxl = (const float*)d_in[5];
    const float* Wxr = (const float*)d_in[6];
    const float* bxp = (const float*)d_in[7];
    const float* Whl = (const float*)d_in[8];
    const float* Whr = (const float*)d_in[9];
    const float* bhp = (const float*)d_in[10];
    const float* wcp = (const float*)d_in[11];
    const float* bgp = (const float*)d_in[12];
    float* outp = (float*)d_out;

    // workspace layout (16B aligned), ~23.7 MB
    char* ws = (char*)d_ws;
    int* counts = (int*)(ws + 0);                             //    80,000 B
    int* cursor = (int*)(ws + 80128);                         //    80,000 B
    unsigned int* s_p = (unsigned int*)(ws + 160256);         // 2,560,000 B
    unsigned short* XHp  = (unsigned short*)(ws + 2720256);   // 10,240,000 B
    unsigned short* AGGp = (unsigned short*)(ws + 12976640);  // 10,240,000 B
    unsigned short* Wtp  = (unsigned short*)(ws + 23233024);  //   524,288 B
    float* biasp = (float*)(ws + 23757312);                   //     2,048 B
    int* tileCtr = (int*)(ws + 23759360);                     //         4 B

    // size the cooperative grid from actual occupancy (pure host query; graph-safe)
    int maxBlkPerCU = 0;
    (void)hipOccupancyMaxActiveBlocksPerMultiprocessor(&maxBlkPerCU, fused_kernel, NTHR, 0);
    int nblk = (maxBlkPerCU >= 2) ? 512 : 256;   // multiples of 8 (XCD slicing)

    int pLo = 0, pHi = 5;
    void* args[] = {
        (void*)&srcE, (void*)&dstE, (void*)&ewp, (void*)&X4, (void*)&H4,
        (void*)&Wxl, (void*)&Wxr, (void*)&Whl, (void*)&Whr,
        (void*)&bxp, (void*)&bhp, (void*)&bgp, (void*)&wcp,
        (void*)&Cp, (void*)&outp,
        (void*)&counts, (void*)&cursor, (void*)&s_p,
        (void*)&XHp, (void*)&AGGp, (void*)&Wtp, (void*)&biasp, (void*)&tileCtr,
        (void*)&pLo, (void*)&pHi
    };
    hipError_t err = hipLaunchCooperativeKernel(fused_kernel, dim3(nblk), dim3(NTHR),
                                                args, 0, stream);
    if (err != hipSuccess) {
        // Fallback: phase-at-a-time plain launches (kernel boundaries = sync)
        for (int ph = 0; ph <= 5; ++ph) {
            fused_kernel<<<512, NTHR, 0, stream>>>(
                srcE, dstE, ewp, X4, H4, Wxl, Wxr, Whl, Whr,
                bxp, bhp, bgp, wcp, Cp, outp,
                counts, cursor, s_p, XHp, AGGp, Wtp, biasp, tileCtr, ph, ph);
        }
    }
}

// Round 7
// 286.577 us; speedup vs baseline: 2.1329x; 2.1329x over previous
//
#include <hip/hip_runtime.h>
#include <math.h>

#define NN 20000
#define NE 640000
#define D  128
#define NSLICE 2500        // NN / 8 XCDs
#define NTILES 625         // NN / 32 rows per GEMM tile (exact)

typedef __attribute__((ext_vector_type(8))) short short8;
typedef __attribute__((ext_vector_type(4))) float floatx4;

static __device__ __forceinline__ unsigned short f2bf(float f) {
    union { float f; unsigned int u; } v; v.f = f;
    unsigned int u = v.u;
    u += 0x7fff + ((u >> 16) & 1);   // round-to-nearest-even
    return (unsigned short)(u >> 16);
}
static __device__ __forceinline__ unsigned int pack2bf(float a, float b) {
    return (unsigned int)f2bf(a) | ((unsigned int)f2bf(b) << 16);
}
static __device__ __forceinline__ float bf_lo(unsigned int u) {
    union { unsigned int i; float f; } v; v.i = u << 16; return v.f;
}
static __device__ __forceinline__ float bf_hi(unsigned int u) {
    union { unsigned int i; float f; } v; v.i = u & 0xffff0000u; return v.f;
}
static __device__ __forceinline__ float sigm(float x) { return 1.f / (1.f + __expf(-x)); }
static __device__ __forceinline__ float tanhx(float x) { return 1.f - 2.f / (__expf(2.f * x) + 1.f); }

// Fused independent prep: degree count (atomics), X/H -> bf16 pack, weight
// transpose + bias fuse. NE == NN*32 == 640000 threads exactly.
__global__ void __launch_bounds__(256)
prep_kernel(const int* __restrict__ dst, int* __restrict__ cnt,
            const float4* __restrict__ X4, const float4* __restrict__ H4,
            unsigned int* __restrict__ XH32,
            const float* __restrict__ Wx_l, const float* __restrict__ Wx_r,
            const float* __restrict__ Wh_l, const float* __restrict__ Wh_r,
            const float* __restrict__ bx, const float* __restrict__ bh,
            const float* __restrict__ bg,
            unsigned short* __restrict__ Wt, float* __restrict__ bias) {
    int t = blockIdx.x * 256 + threadIdx.x;  // 0 .. 639999
    atomicAdd(&cnt[dst[t]], 1);
    float4 x = X4[t];
    float4 h = H4[t];
    int n = t >> 5, q = t & 31;
    unsigned int* row = XH32 + n * 128;
    row[2 * q]          = pack2bf(x.x, x.y);
    row[2 * q + 1]      = pack2bf(x.z, x.w);
    row[64 + 2 * q]     = pack2bf(h.x, h.y);
    row[64 + 2 * q + 1] = pack2bf(h.z, h.w);
    if (t < 512 * 512) {
        int j = t >> 9, k = t & 511, g = j >> 7, o = j & 127;
        float w;
        if (k < 128)      w = Wx_l[g * 16384 + k * 128 + o];
        else if (k < 256) w = Wx_r[g * 16384 + (k - 128) * 128 + o];
        else if (k < 384) w = Wh_l[g * 16384 + (k - 256) * 128 + o];
        else              w = Wh_r[g * 16384 + (k - 384) * 128 + o];
        Wt[j * 512 + k] = f2bf(w);
        if (k == 0) bias[j] = bx[g * 128 + o] + bh[g * 128 + o] + bg[g * 128 + o];
    }
}

// exclusive prefix of counts -> cursor
__global__ void scan_kernel(const int* __restrict__ cnt, int* __restrict__ cursor) {
    __shared__ int part[1024];
    int t = threadIdx.x;
    const int PER = 20;
    int base = t * PER;
    int c[PER];
    int local = 0;
#pragma unroll
    for (int i = 0; i < PER; ++i) {
        int idx = base + i;
        c[i] = (idx < NN) ? cnt[idx] : 0;
        local += c[i];
    }
    part[t] = local;
    __syncthreads();
    for (int off = 1; off < 1024; off <<= 1) {
        int v = (t >= off) ? part[t - off] : 0;
        __syncthreads();
        part[t] += v;
        __syncthreads();
    }
    int run = part[t] - local;
#pragma unroll
    for (int i = 0; i < PER; ++i) {
        int idx = base + i;
        if (idx < NN) { cursor[idx] = run; run += c[i]; }
    }
}

// XCD-sliced CSR fill: block handles dst-slice s = blockIdx&7 over an
// 8000-edge chunk; slice's CSR range is contiguous -> single-XCD line dirtying.
// Entry packed to 4B: src (15 bits) | bf16(weight) << 16.
__global__ void __launch_bounds__(256)
fill_kernel(const int* __restrict__ src, const int* __restrict__ dst,
            const float* __restrict__ ew, int* __restrict__ cursor,
            unsigned int* __restrict__ s_p) {
    int s = blockIdx.x & 7;
    int chunk = blockIdx.x >> 3;
    int lo = s * NSLICE, hi = lo + NSLICE;
    int e0 = chunk * 8000;
    for (int e = e0 + threadIdx.x; e < e0 + 8000; e += 256) {
        int d = dst[e];
        if (d >= lo && d < hi) {
            int p = atomicAdd(&cursor[d], 1);
            s_p[p] = (unsigned int)src[e] | ((unsigned int)f2bf(ew[e]) << 16);
        }
    }
}

// One wave per node (lane owns 8 B of the 512 B row). 16-edge manual unroll:
// 16 independent row gathers in flight per lane. Block->node mapping matches
// fill's XCD slicing so CSR segment reads hit the local L2.
__global__ void __launch_bounds__(256)
aggregate_kernel(const uint2* __restrict__ XH64,
                 const int* __restrict__ cursor,
                 const unsigned int* __restrict__ s_p,
                 uint2* __restrict__ AGG64) {
    int wv = threadIdx.x >> 6, lane = threadIdx.x & 63;
    int b = blockIdx.x;                 // 0..4999
    int s = b & 7, j = b >> 3;          // j: 0..624
    int n = s * NSLICE + j * 4 + wv;
    int s1 = cursor[n];
    int s0 = (n > 0) ? cursor[n - 1] : 0;
    float a0 = 0.f, a1 = 0.f, a2 = 0.f, a3 = 0.f;
    int i = s0;
    for (; i + 16 <= s1; i += 16) {
        unsigned int e[16];
        uint2 u[16];
#pragma unroll
        for (int k = 0; k < 16; ++k) e[k] = s_p[i + k];
#pragma unroll
        for (int k = 0; k < 16; ++k) u[k] = XH64[(size_t)(e[k] & 0xffff) * 64 + lane];
#pragma unroll
        for (int k = 0; k < 16; ++k) {
            float w = __int_as_float(e[k] & 0xffff0000u);
            a0 += bf_lo(u[k].x) * w;
            a1 += bf_hi(u[k].x) * w;
            a2 += bf_lo(u[k].y) * w;
            a3 += bf_hi(u[k].y) * w;
        }
    }
    for (; i + 4 <= s1; i += 4) {
        unsigned int e[4];
        uint2 u[4];
#pragma unroll
        for (int k = 0; k < 4; ++k) e[k] = s_p[i + k];
#pragma unroll
        for (int k = 0; k < 4; ++k) u[k] = XH64[(size_t)(e[k] & 0xffff) * 64 + lane];
#pragma unroll
        for (int k = 0; k < 4; ++k) {
            float w = __int_as_float(e[k] & 0xffff0000u);
            a0 += bf_lo(u[k].x) * w;
            a1 += bf_hi(u[k].x) * w;
            a2 += bf_lo(u[k].y) * w;
            a3 += bf_hi(u[k].y) * w;
        }
    }
    for (; i < s1; ++i) {
        unsigned int e = s_p[i];
        float w = __int_as_float(e & 0xffff0000u);
        uint2 u = XH64[(size_t)(e & 0xffff) * 64 + lane];
        a0 += bf_lo(u.x) * w;
        a1 += bf_hi(u.x) * w;
        a2 += bf_lo(u.y) * w;
        a3 += bf_hi(u.y) * w;
    }
    float inv = (s1 > s0) ? 1.0f / (float)(s1 - s0) : 1.0f;
    uint2 r;
    r.x = pack2bf(a0 * inv, a1 * inv);
    r.y = pack2bf(a2 * inv, a3 * inv);
    AGG64[(size_t)n * 64 + lane] = r;
}

// Fused GEMM + peephole-LSTM. LDS-free, register-direct.
// 625 blocks x 32 rows; 4 waves; wave wv owns in-gate cols [wv*32, wv*32+32)
// for ALL 4 gates -> all gates of an output element in one lane ->
// in-register LSTM epilogue. B-frags read directly from L2-resident Wt
// (512 KB); A-frags from XH/AGG with one-iteration prefetch.
__global__ void __launch_bounds__(256)
gemm_lstm_kernel(const unsigned short* __restrict__ XH,
                 const unsigned short* __restrict__ AGG,
                 const unsigned short* __restrict__ Wt,
                 const float* __restrict__ bias,
                 const float* __restrict__ wc,
                 const float* __restrict__ C,
                 float* __restrict__ out) {
    int tid = threadIdx.x;
    int wv = tid >> 6, lane = tid & 63;
    int lm = lane & 15, lq = lane >> 4;
    int m0 = blockIdx.x * 32;

    const unsigned short* brow = Wt + (size_t)((wv << 5) + lm) * 512 + lq * 8;

    floatx4 acc[2][4][2];
#pragma unroll
    for (int mt = 0; mt < 2; ++mt)
#pragma unroll
        for (int g = 0; g < 4; ++g)
#pragma unroll
            for (int nt = 0; nt < 2; ++nt) acc[mt][g][nt] = (floatx4)(0.f);

    // A prefetch for kb=0 (segment aggX, offset 0 in AGG)
    short8 ca0, ca1;
    {
        const unsigned short* ar = AGG + (size_t)(m0 + lm) * 256 + lq * 8;
        ca0 = *(const short8*)ar;
        ca1 = *(const short8*)(ar + 16 * 256);
    }

    for (int it = 0; it < 16; ++it) {
        int kb = it * 32;
        // B frags for this K-chunk (direct from L2)
        short8 cb[4][2];
        const unsigned short* bk = brow + kb;
#pragma unroll
        for (int g = 0; g < 4; ++g)
#pragma unroll
            for (int nt = 0; nt < 2; ++nt)
                cb[g][nt] = *(const short8*)(bk + (size_t)((g << 7) + (nt << 4)) * 512);
        // A prefetch for next iter
        short8 na0, na1;
        if (it < 15) {
            int kn = kb + 32;
            const unsigned short* ab = (kn & 128) ? XH : AGG;
            int aoff = (kn & 127) | ((kn & 256) >> 1);
            const unsigned short* arn = ab + (size_t)(m0 + lm) * 256 + aoff + lq * 8;
            na0 = *(const short8*)arn;
            na1 = *(const short8*)(arn + 16 * 256);
        }
#pragma unroll
        for (int g = 0; g < 4; ++g)
#pragma unroll
            for (int nt = 0; nt < 2; ++nt) {
                acc[0][g][nt] = __builtin_amdgcn_mfma_f32_16x16x32_bf16(ca0, cb[g][nt], acc[0][g][nt], 0, 0, 0);
                acc[1][g][nt] = __builtin_amdgcn_mfma_f32_16x16x32_bf16(ca1, cb[g][nt], acc[1][g][nt], 0, 0, 0);
            }
        ca0 = na0; ca1 = na1;
    }

    // epilogue: bias/peephole loads here (keeps K-loop register pressure low)
    float bG[4][2], wP[3][2];
#pragma unroll
    for (int nt = 0; nt < 2; ++nt) {
        int cg0 = (wv << 5) + (nt << 4) + lm;
#pragma unroll
        for (int g = 0; g < 4; ++g) bG[g][nt] = bias[(g << 7) + cg0];
#pragma unroll
        for (int j = 0; j < 3; ++j) wP[j][nt] = wc[j * 128 + cg0];
    }

#pragma unroll
    for (int mt = 0; mt < 2; ++mt)
#pragma unroll
        for (int r = 0; r < 4; ++r) {
            int row = m0 + mt * 16 + lq * 4 + r;   // 625*32 == NN exact, no guard
#pragma unroll
            for (int nt = 0; nt < 2; ++nt) {
                int cg0 = (wv << 5) + (nt << 4) + lm;
                float c = C[(size_t)row * D + cg0];
                float pi = acc[mt][0][nt][r] + bG[0][nt] + wP[0][nt] * c;
                float pf = acc[mt][1][nt][r] + bG[1][nt] + wP[1][nt] * c;
                float pt = acc[mt][2][nt][r] + bG[2][nt];
                float po = acc[mt][3][nt][r] + bG[3][nt];
                float I = sigm(pi);
                float F = sigm(pf);
                float T = tanhx(pt);
                float cn = F * c + I * T;
                float O = sigm(po + wP[2][nt] * cn);
                out[(size_t)row * D + cg0] = O * tanhx(cn);
                out[(size_t)NN * D + (size_t)row * D + cg0] = cn;
            }
        }
}

extern "C" void kernel_launch(void* const* d_in, const int* in_sizes, int n_in,
                              void* d_out, int out_size, void* d_ws, size_t ws_size,
                              hipStream_t stream) {
    const float* X  = (const float*)d_in[0];
    const int* ei   = (const int*)d_in[1];
    const float* ew = (const float*)d_in[2];
    const float* H  = (const float*)d_in[3];
    const float* C  = (const float*)d_in[4];
    const float* Wx_l = (const float*)d_in[5];
    const float* Wx_r = (const float*)d_in[6];
    const float* bx   = (const float*)d_in[7];
    const float* Wh_l = (const float*)d_in[8];
    const float* Wh_r = (const float*)d_in[9];
    const float* bh   = (const float*)d_in[10];
    const float* wc   = (const float*)d_in[11];
    const float* bg   = (const float*)d_in[12];
    float* out = (float*)d_out;

    const int* src = ei;
    const int* dst = ei + NE;

    // workspace layout (16B aligned), ~23.7 MB
    char* ws = (char*)d_ws;
    int* counts = (int*)(ws + 0);                             //    80,000 B
    int* cursor = (int*)(ws + 80128);                         //    80,000 B
    unsigned int* s_p = (unsigned int*)(ws + 160256);         // 2,560,000 B
    unsigned short* XH  = (unsigned short*)(ws + 2720256);    // 10,240,000 B
    unsigned short* AGG = (unsigned short*)(ws + 12960384);   // 10,240,000 B
    unsigned short* Wt  = (unsigned short*)(ws + 23200384);   //   524,288 B
    float* bias = (float*)(ws + 23724672);                    //     2,048 B

    hipMemsetAsync(counts, 0, NN * sizeof(int), stream);
    prep_kernel<<<NE / 256, 256, 0, stream>>>(dst, counts, (const float4*)X, (const float4*)H,
                                              (unsigned int*)XH, Wx_l, Wx_r, Wh_l, Wh_r,
                                              bx, bh, bg, Wt, bias);
    scan_kernel<<<1, 1024, 0, stream>>>(counts, cursor);
    fill_kernel<<<8 * (NE / 8000), 256, 0, stream>>>(src, dst, ew, cursor, s_p);
    aggregate_kernel<<<NN / 4, 256, 0, stream>>>((const uint2*)XH, cursor, s_p,
                                                 (uint2*)AGG);
    gemm_lstm_kernel<<<NTILES, 256, 0, stream>>>(XH, AGG, Wt, bias, wc, C, out);
}

// Round 8
// 256.305 us; speedup vs baseline: 2.3848x; 1.1181x over previous
//
#include <hip/hip_runtime.h>
#include <math.h>

#define NN 20000
#define NE 640000
#define D  128
#define NSLICE 2500        // NN / 8 XCDs
#define NTILES 625         // NN / 32 rows per GEMM tile (exact)

typedef __attribute__((ext_vector_type(8))) short short8;
typedef __attribute__((ext_vector_type(4))) float floatx4;

static __device__ __forceinline__ unsigned short f2bf(float f) {
    union { float f; unsigned int u; } v; v.f = f;
    unsigned int u = v.u;
    u += 0x7fff + ((u >> 16) & 1);   // round-to-nearest-even
    return (unsigned short)(u >> 16);
}
static __device__ __forceinline__ unsigned int pack2bf(float a, float b) {
    return (unsigned int)f2bf(a) | ((unsigned int)f2bf(b) << 16);
}
static __device__ __forceinline__ float bf_lo(unsigned int u) {
    union { unsigned int i; float f; } v; v.i = u << 16; return v.f;
}
static __device__ __forceinline__ float bf_hi(unsigned int u) {
    union { unsigned int i; float f; } v; v.i = u & 0xffff0000u; return v.f;
}
static __device__ __forceinline__ float sigm(float x) { return 1.f / (1.f + __expf(-x)); }
static __device__ __forceinline__ float tanhx(float x) { return 1.f - 2.f / (__expf(2.f * x) + 1.f); }

static __device__ __forceinline__ void load_lds16(const void* g, void* l) {
    __builtin_amdgcn_global_load_lds(
        (const __attribute__((address_space(1))) unsigned int*)g,
        (__attribute__((address_space(3))) unsigned int*)l, 16, 0, 0);
}

// Fused independent prep: degree count (atomics), X/H -> bf16 pack, weight
// transpose into the LDS-image swizzled layout, bias fuse.
// Wsz layout (shorts): idx = ci*16384 + jg*4096 + col*8 + off
//   where k = ci*32 + jg*8 + off (ci: 32-k chunk, jg: k-quad, off: k within 8)
// so staging chunk ci is one contiguous 32 KB copy, and ds_read_b128 of a
// B-frag (16 consecutive cols x 16 B) is LDS-bank-conflict-free.
__global__ void __launch_bounds__(256)
prep_kernel(const int* __restrict__ dst, int* __restrict__ cnt,
            const float4* __restrict__ X4, const float4* __restrict__ H4,
            unsigned int* __restrict__ XH32,
            const float* __restrict__ Wx_l, const float* __restrict__ Wx_r,
            const float* __restrict__ Wh_l, const float* __restrict__ Wh_r,
            const float* __restrict__ bx, const float* __restrict__ bh,
            const float* __restrict__ bg,
            unsigned short* __restrict__ Wsz, float* __restrict__ bias) {
    int t = blockIdx.x * 256 + threadIdx.x;  // 0 .. 639999
    atomicAdd(&cnt[dst[t]], 1);
    float4 x = X4[t];
    float4 h = H4[t];
    int n = t >> 5, q = t & 31;
    unsigned int* row = XH32 + n * 128;
    row[2 * q]          = pack2bf(x.x, x.y);
    row[2 * q + 1]      = pack2bf(x.z, x.w);
    row[64 + 2 * q]     = pack2bf(h.x, h.y);
    row[64 + 2 * q + 1] = pack2bf(h.z, h.w);
    if (t < 512 * 512) {
        int j = t >> 9, k = t & 511, g = j >> 7, o = j & 127;
        float w;
        if (k < 128)      w = Wx_l[g * 16384 + k * 128 + o];
        else if (k < 256) w = Wx_r[g * 16384 + (k - 128) * 128 + o];
        else if (k < 384) w = Wh_l[g * 16384 + (k - 256) * 128 + o];
        else              w = Wh_r[g * 16384 + (k - 384) * 128 + o];
        int ci = k >> 5, jg = (k >> 3) & 3, off = k & 7;
        Wsz[ci * 16384 + jg * 4096 + j * 8 + off] = f2bf(w);
        if (k == 0) bias[j] = bx[g * 128 + o] + bh[g * 128 + o] + bg[g * 128 + o];
    }
}

// exclusive prefix of counts -> cursor
__global__ void scan_kernel(const int* __restrict__ cnt, int* __restrict__ cursor) {
    __shared__ int part[1024];
    int t = threadIdx.x;
    const int PER = 20;
    int base = t * PER;
    int c[PER];
    int local = 0;
#pragma unroll
    for (int i = 0; i < PER; ++i) {
        int idx = base + i;
        c[i] = (idx < NN) ? cnt[idx] : 0;
        local += c[i];
    }
    part[t] = local;
    __syncthreads();
    for (int off = 1; off < 1024; off <<= 1) {
        int v = (t >= off) ? part[t - off] : 0;
        __syncthreads();
        part[t] += v;
        __syncthreads();
    }
    int run = part[t] - local;
#pragma unroll
    for (int i = 0; i < PER; ++i) {
        int idx = base + i;
        if (idx < NN) { cursor[idx] = run; run += c[i]; }
    }
}

// XCD-sliced CSR fill: block handles dst-slice s = blockIdx&7 over an
// 8000-edge chunk; slice's CSR range is contiguous -> single-XCD line dirtying.
// Entry packed to 4B: src (15 bits) | bf16(weight) << 16.
__global__ void __launch_bounds__(256)
fill_kernel(const int* __restrict__ src, const int* __restrict__ dst,
            const float* __restrict__ ew, int* __restrict__ cursor,
            unsigned int* __restrict__ s_p) {
    int s = blockIdx.x & 7;
    int chunk = blockIdx.x >> 3;
    int lo = s * NSLICE, hi = lo + NSLICE;
    int e0 = chunk * 8000;
    for (int e = e0 + threadIdx.x; e < e0 + 8000; e += 256) {
        int d = dst[e];
        if (d >= lo && d < hi) {
            int p = atomicAdd(&cursor[d], 1);
            s_p[p] = (unsigned int)src[e] | ((unsigned int)f2bf(ew[e]) << 16);
        }
    }
}

// One wave per node (lane owns 8 B of the 512 B row). 16-edge manual unroll:
// 16 independent row gathers in flight per lane. Block->node mapping matches
// fill's XCD slicing so CSR segment reads hit the local L2.
__global__ void __launch_bounds__(256)
aggregate_kernel(const uint2* __restrict__ XH64,
                 const int* __restrict__ cursor,
                 const unsigned int* __restrict__ s_p,
                 uint2* __restrict__ AGG64) {
    int wv = threadIdx.x >> 6, lane = threadIdx.x & 63;
    int b = blockIdx.x;                 // 0..4999
    int s = b & 7, j = b >> 3;          // j: 0..624
    int n = s * NSLICE + j * 4 + wv;
    int s1 = cursor[n];
    int s0 = (n > 0) ? cursor[n - 1] : 0;
    float a0 = 0.f, a1 = 0.f, a2 = 0.f, a3 = 0.f;
    int i = s0;
    for (; i + 16 <= s1; i += 16) {
        unsigned int e[16];
        uint2 u[16];
#pragma unroll
        for (int k = 0; k < 16; ++k) e[k] = s_p[i + k];
#pragma unroll
        for (int k = 0; k < 16; ++k) u[k] = XH64[(size_t)(e[k] & 0xffff) * 64 + lane];
#pragma unroll
        for (int k = 0; k < 16; ++k) {
            float w = __int_as_float(e[k] & 0xffff0000u);
            a0 += bf_lo(u[k].x) * w;
            a1 += bf_hi(u[k].x) * w;
            a2 += bf_lo(u[k].y) * w;
            a3 += bf_hi(u[k].y) * w;
        }
    }
    for (; i + 4 <= s1; i += 4) {
        unsigned int e[4];
        uint2 u[4];
#pragma unroll
        for (int k = 0; k < 4; ++k) e[k] = s_p[i + k];
#pragma unroll
        for (int k = 0; k < 4; ++k) u[k] = XH64[(size_t)(e[k] & 0xffff) * 64 + lane];
#pragma unroll
        for (int k = 0; k < 4; ++k) {
            float w = __int_as_float(e[k] & 0xffff0000u);
            a0 += bf_lo(u[k].x) * w;
            a1 += bf_hi(u[k].x) * w;
            a2 += bf_lo(u[k].y) * w;
            a3 += bf_hi(u[k].y) * w;
        }
    }
    for (; i < s1; ++i) {
        unsigned int e = s_p[i];
        float w = __int_as_float(e & 0xffff0000u);
        uint2 u = XH64[(size_t)(e & 0xffff) * 64 + lane];
        a0 += bf_lo(u.x) * w;
        a1 += bf_hi(u.x) * w;
        a2 += bf_lo(u.y) * w;
        a3 += bf_hi(u.y) * w;
    }
    float inv = (s1 > s0) ? 1.0f / (float)(s1 - s0) : 1.0f;
    uint2 r;
    r.x = pack2bf(a0 * inv, a1 * inv);
    r.y = pack2bf(a2 * inv, a3 * inv);
    AGG64[(size_t)n * 64 + lane] = r;
}

// Fused GEMM + peephole-LSTM. 625 blocks x 32 rows x 512 cols, 4 waves.
// B staged per 32-K chunk from the pre-swizzled Wsz via contiguous
// global_load_lds dwordx4 into a double-buffered 32 KB LDS image whose
// ds_read_b128 frag reads are bank-conflict-free. Wave wv owns in-gate cols
// [wv*32, wv*32+32) for ALL 4 gates -> in-register LSTM epilogue.
__global__ void __launch_bounds__(256)
gemm_lstm_kernel(const unsigned short* __restrict__ XH,
                 const unsigned short* __restrict__ AGG,
                 const unsigned short* __restrict__ Wsz,
                 const float* __restrict__ bias,
                 const float* __restrict__ wc,
                 const float* __restrict__ C,
                 float* __restrict__ out) {
    __shared__ __align__(16) short Bs[2][16384];  // [buf][lq*4096 + col*8 + off]

    int tid = threadIdx.x;
    int wv = tid >> 6, lane = tid & 63;
    int lm = lane & 15, lq = lane >> 4;
    int m0 = blockIdx.x * 32;

    floatx4 acc[2][4][2];
#pragma unroll
    for (int mt = 0; mt < 2; ++mt)
#pragma unroll
        for (int g = 0; g < 4; ++g)
#pragma unroll
            for (int nt = 0; nt < 2; ++nt) acc[mt][g][nt] = (floatx4)(0.f);

    // stage chunk 0 into buf 0: wave wv copies shorts [wv*4096, wv*4096+4096)
    // in 8 calls of 1024 B (64 lanes x 16 B), global and LDS both contiguous.
#pragma unroll
    for (int i = 0; i < 8; ++i)
        load_lds16(Wsz + (wv * 8 + i) * 512 + lane * 8, &Bs[0][(wv * 8 + i) * 512]);

    // A prefetch for kb=0 (segment aggX, offset 0 in AGG)
    short8 ca0, ca1;
    {
        const unsigned short* ar = AGG + (size_t)(m0 + lm) * 256 + lq * 8;
        ca0 = *(const short8*)ar;
        ca1 = *(const short8*)(ar + 16 * 256);
    }

    for (int it = 0; it < 16; ++it) {
        __syncthreads();   // drains staging (vmcnt0) + guards buffer reuse
        if (it < 15) {
            const unsigned short* wb = Wsz + (it + 1) * 16384;
            short* lb = Bs[(it + 1) & 1];
#pragma unroll
            for (int i = 0; i < 8; ++i)
                load_lds16(wb + (wv * 8 + i) * 512 + lane * 8, &lb[(wv * 8 + i) * 512]);
        }
        // A prefetch for next iter
        short8 na0, na1;
        if (it < 15) {
            int kn = (it + 1) * 32;
            const unsigned short* ab = (kn & 128) ? XH : AGG;
            int aoff = (kn & 127) | ((kn & 256) >> 1);
            const unsigned short* arn = ab + (size_t)(m0 + lm) * 256 + aoff + lq * 8;
            na0 = *(const short8*)arn;
            na1 = *(const short8*)(arn + 16 * 256);
        }
        // B frags from LDS (conflict-free) + MFMA
        const short* bsc = Bs[it & 1];
#pragma unroll
        for (int g = 0; g < 4; ++g)
#pragma unroll
            for (int nt = 0; nt < 2; ++nt) {
                int col = (g << 7) + (wv << 5) + (nt << 4) + lm;
                short8 b = *(const short8*)&bsc[(lq << 12) + (col << 3)];
                acc[0][g][nt] = __builtin_amdgcn_mfma_f32_16x16x32_bf16(ca0, b, acc[0][g][nt], 0, 0, 0);
                acc[1][g][nt] = __builtin_amdgcn_mfma_f32_16x16x32_bf16(ca1, b, acc[1][g][nt], 0, 0, 0);
            }
        ca0 = na0; ca1 = na1;
    }

    // epilogue: bias/peephole loads here (keeps K-loop register pressure low)
    float bG[4][2], wP[3][2];
#pragma unroll
    for (int nt = 0; nt < 2; ++nt) {
        int cg0 = (wv << 5) + (nt << 4) + lm;
#pragma unroll
        for (int g = 0; g < 4; ++g) bG[g][nt] = bias[(g << 7) + cg0];
#pragma unroll
        for (int j = 0; j < 3; ++j) wP[j][nt] = wc[j * 128 + cg0];
    }

#pragma unroll
    for (int mt = 0; mt < 2; ++mt)
#pragma unroll
        for (int r = 0; r < 4; ++r) {
            int row = m0 + mt * 16 + lq * 4 + r;   // 625*32 == NN exact, no guard
#pragma unroll
            for (int nt = 0; nt < 2; ++nt) {
                int cg0 = (wv << 5) + (nt << 4) + lm;
                float c = C[(size_t)row * D + cg0];
                float pi = acc[mt][0][nt][r] + bG[0][nt] + wP[0][nt] * c;
                float pf = acc[mt][1][nt][r] + bG[1][nt] + wP[1][nt] * c;
                float pt = acc[mt][2][nt][r] + bG[2][nt];
                float po = acc[mt][3][nt][r] + bG[3][nt];
                float I = sigm(pi);
                float F = sigm(pf);
                float T = tanhx(pt);
                float cn = F * c + I * T;
                float O = sigm(po + wP[2][nt] * cn);
                out[(size_t)row * D + cg0] = O * tanhx(cn);
                out[(size_t)NN * D + (size_t)row * D + cg0] = cn;
            }
        }
}

extern "C" void kernel_launch(void* const* d_in, const int* in_sizes, int n_in,
                              void* d_out, int out_size, void* d_ws, size_t ws_size,
                              hipStream_t stream) {
    const float* X  = (const float*)d_in[0];
    const int* ei   = (const int*)d_in[1];
    const float* ew = (const float*)d_in[2];
    const float* H  = (const float*)d_in[3];
    const float* C  = (const float*)d_in[4];
    const float* Wx_l = (const float*)d_in[5];
    const float* Wx_r = (const float*)d_in[6];
    const float* bx   = (const float*)d_in[7];
    const float* Wh_l = (const float*)d_in[8];
    const float* Wh_r = (const float*)d_in[9];
    const float* bh   = (const float*)d_in[10];
    const float* wc   = (const float*)d_in[11];
    const float* bg   = (const float*)d_in[12];
    float* out = (float*)d_out;

    const int* src = ei;
    const int* dst = ei + NE;

    // workspace layout (16B aligned), ~23.7 MB
    char* ws = (char*)d_ws;
    int* counts = (int*)(ws + 0);                             //    80,000 B
    int* cursor = (int*)(ws + 80128);                         //    80,000 B
    unsigned int* s_p = (unsigned int*)(ws + 160256);         // 2,560,000 B
    unsigned short* XH  = (unsigned short*)(ws + 2720256);    // 10,240,000 B
    unsigned short* AGG = (unsigned short*)(ws + 12960384);   // 10,240,000 B
    unsigned short* Wsz = (unsigned short*)(ws + 23200384);   //   524,288 B
    float* bias = (float*)(ws + 23724672);                    //     2,048 B

    hipMemsetAsync(counts, 0, NN * sizeof(int), stream);
    prep_kernel<<<NE / 256, 256, 0, stream>>>(dst, counts, (const float4*)X, (const float4*)H,
                                              (unsigned int*)XH, Wx_l, Wx_r, Wh_l, Wh_r,
                                              bx, bh, bg, Wsz, bias);
    scan_kernel<<<1, 1024, 0, stream>>>(counts, cursor);
    fill_kernel<<<8 * (NE / 8000), 256, 0, stream>>>(src, dst, ew, cursor, s_p);
    aggregate_kernel<<<NN / 4, 256, 0, stream>>>((const uint2*)XH, cursor, s_p,
                                                 (uint2*)AGG);
    gemm_lstm_kernel<<<NTILES, 256, 0, stream>>>(XH, AGG, Wsz, bias, wc, C, out);
}

// Round 9
// 224.758 us; speedup vs baseline: 2.7195x; 1.1404x over previous
//
#include <hip/hip_runtime.h>
#include <math.h>

#define NN 20000
#define NE 640000
#define D  128
#define NSLICE 2500        // NN / 8 XCDs
#define NTILES 625         // NN / 32 rows per GEMM tile (exact)
#define SEG 128            // per-node bump-allocated segment (max degree; mean 32)

typedef __attribute__((ext_vector_type(8))) short short8;
typedef __attribute__((ext_vector_type(4))) float floatx4;

static __device__ __forceinline__ unsigned short f2bf(float f) {
    union { float f; unsigned int u; } v; v.f = f;
    unsigned int u = v.u;
    u += 0x7fff + ((u >> 16) & 1);   // round-to-nearest-even
    return (unsigned short)(u >> 16);
}
static __device__ __forceinline__ unsigned int pack2bf(float a, float b) {
    return (unsigned int)f2bf(a) | ((unsigned int)f2bf(b) << 16);
}
static __device__ __forceinline__ float bf_lo(unsigned int u) {
    union { unsigned int i; float f; } v; v.i = u << 16; return v.f;
}
static __device__ __forceinline__ float bf_hi(unsigned int u) {
    union { unsigned int i; float f; } v; v.i = u & 0xffff0000u; return v.f;
}
static __device__ __forceinline__ float sigm(float x) { return 1.f / (1.f + __expf(-x)); }
static __device__ __forceinline__ float tanhx(float x) { return 1.f - 2.f / (__expf(2.f * x) + 1.f); }

static __device__ __forceinline__ void load_lds16(const void* g, void* l) {
    __builtin_amdgcn_global_load_lds(
        (const __attribute__((address_space(1))) unsigned int*)g,
        (__attribute__((address_space(3))) unsigned int*)l, 16, 0, 0);
}

// Fused prep + CSR fill (bump allocation -> no scan pass):
//  (a) grid-stride: X/H -> bf16 pack into XH; weight transpose into the
//      LDS-image swizzled Wsz layout; bias fuse.
//  (b) XCD-sliced fill: block b handles dst-slice s=b&7 over an 8000-edge
//      chunk; entry s_p[d*SEG + p], p = atomicAdd(&cnt[d],1). A node's 512 B
//      segment is written only from its slice's blocks -> single-XCD line
//      dirtying (no cross-XCD write-back amplification).
// Wsz layout (shorts): idx = ci*16384 + jg*4096 + col*8 + off, k = ci*32+jg*8+off.
__global__ void __launch_bounds__(256)
prep_fill_kernel(const int* __restrict__ src, const int* __restrict__ dst,
                 const float* __restrict__ ew, int* __restrict__ cnt,
                 unsigned int* __restrict__ s_p,
                 const float4* __restrict__ X4, const float4* __restrict__ H4,
                 unsigned int* __restrict__ XH32,
                 const float* __restrict__ Wx_l, const float* __restrict__ Wx_r,
                 const float* __restrict__ Wh_l, const float* __restrict__ Wh_r,
                 const float* __restrict__ bx, const float* __restrict__ bh,
                 const float* __restrict__ bg,
                 unsigned short* __restrict__ Wsz, float* __restrict__ bias) {
    int tid = threadIdx.x, b = blockIdx.x;       // 640 blocks x 256 threads
    // (a) packing, grid-stride (4 iters)
    for (int t = b * 256 + tid; t < NE; t += 640 * 256) {
        float4 x = X4[t];
        float4 h = H4[t];
        int n = t >> 5, q = t & 31;
        unsigned int* row = XH32 + n * 128;
        row[2 * q]          = pack2bf(x.x, x.y);
        row[2 * q + 1]      = pack2bf(x.z, x.w);
        row[64 + 2 * q]     = pack2bf(h.x, h.y);
        row[64 + 2 * q + 1] = pack2bf(h.z, h.w);
        if (t < 512 * 512) {
            int j = t >> 9, k = t & 511, g = j >> 7, o = j & 127;
            float w;
            if (k < 128)      w = Wx_l[g * 16384 + k * 128 + o];
            else if (k < 256) w = Wx_r[g * 16384 + (k - 128) * 128 + o];
            else if (k < 384) w = Wh_l[g * 16384 + (k - 256) * 128 + o];
            else              w = Wh_r[g * 16384 + (k - 384) * 128 + o];
            int ci = k >> 5, jg = (k >> 3) & 3, off = k & 7;
            Wsz[ci * 16384 + jg * 4096 + j * 8 + off] = f2bf(w);
            if (k == 0) bias[j] = bx[g * 128 + o] + bh[g * 128 + o] + bg[g * 128 + o];
        }
    }
    // (b) slice-filtered bump fill
    int s = b & 7, chunk = b >> 3;               // 80 chunks x 8000 edges
    int lo = s * NSLICE, hi = lo + NSLICE;
    int e0 = chunk * 8000;
    for (int e = e0 + tid; e < e0 + 8000; e += 256) {
        int d = dst[e];
        if (d >= lo && d < hi) {
            int p = atomicAdd(&cnt[d], 1);
            if (p < SEG) s_p[d * SEG + p] = (unsigned int)src[e] | ((unsigned int)f2bf(ew[e]) << 16);
        }
    }
}

// One wave per node (lane owns 8 B of the 512 B row). 16-edge manual unroll:
// 16 independent row gathers in flight per lane. Block->node mapping matches
// fill's XCD slicing so segment reads hit the local L2.
__global__ void __launch_bounds__(256)
aggregate_kernel(const uint2* __restrict__ XH64,
                 const int* __restrict__ cnt,
                 const unsigned int* __restrict__ s_p,
                 uint2* __restrict__ AGG64) {
    int wv = threadIdx.x >> 6, lane = threadIdx.x & 63;
    int b = blockIdx.x;                 // 0..4999
    int s = b & 7, j = b >> 3;          // j: 0..624
    int n = s * NSLICE + j * 4 + wv;
    int deg = cnt[n];
    int m = (deg < SEG) ? deg : SEG;
    const unsigned int* seg = s_p + (size_t)n * SEG;
    float a0 = 0.f, a1 = 0.f, a2 = 0.f, a3 = 0.f;
    int i = 0;
    for (; i + 16 <= m; i += 16) {
        unsigned int e[16];
        uint2 u[16];
#pragma unroll
        for (int k = 0; k < 16; ++k) e[k] = seg[i + k];
#pragma unroll
        for (int k = 0; k < 16; ++k) u[k] = XH64[(size_t)(e[k] & 0xffff) * 64 + lane];
#pragma unroll
        for (int k = 0; k < 16; ++k) {
            float w = __int_as_float(e[k] & 0xffff0000u);
            a0 += bf_lo(u[k].x) * w;
            a1 += bf_hi(u[k].x) * w;
            a2 += bf_lo(u[k].y) * w;
            a3 += bf_hi(u[k].y) * w;
        }
    }
    for (; i + 4 <= m; i += 4) {
        unsigned int e[4];
        uint2 u[4];
#pragma unroll
        for (int k = 0; k < 4; ++k) e[k] = seg[i + k];
#pragma unroll
        for (int k = 0; k < 4; ++k) u[k] = XH64[(size_t)(e[k] & 0xffff) * 64 + lane];
#pragma unroll
        for (int k = 0; k < 4; ++k) {
            float w = __int_as_float(e[k] & 0xffff0000u);
            a0 += bf_lo(u[k].x) * w;
            a1 += bf_hi(u[k].x) * w;
            a2 += bf_lo(u[k].y) * w;
            a3 += bf_hi(u[k].y) * w;
        }
    }
    for (; i < m; ++i) {
        unsigned int e = seg[i];
        float w = __int_as_float(e & 0xffff0000u);
        uint2 u = XH64[(size_t)(e & 0xffff) * 64 + lane];
        a0 += bf_lo(u.x) * w;
        a1 += bf_hi(u.x) * w;
        a2 += bf_lo(u.y) * w;
        a3 += bf_hi(u.y) * w;
    }
    float inv = (deg > 0) ? 1.0f / (float)deg : 1.0f;
    uint2 r;
    r.x = pack2bf(a0 * inv, a1 * inv);
    r.y = pack2bf(a2 * inv, a3 * inv);
    AGG64[(size_t)n * 64 + lane] = r;
}

// Fused GEMM + peephole-LSTM. 625 blocks x 32 rows x 512 cols, 4 waves.
// B staged per 32-K chunk from the pre-swizzled Wsz via contiguous
// global_load_lds dwordx4 into a double-buffered 32 KB LDS image whose
// ds_read_b128 frag reads are bank-conflict-free. Wave wv owns in-gate cols
// [wv*32, wv*32+32) for ALL 4 gates -> in-register LSTM epilogue.
__global__ void __launch_bounds__(256)
gemm_lstm_kernel(const unsigned short* __restrict__ XH,
                 const unsigned short* __restrict__ AGG,
                 const unsigned short* __restrict__ Wsz,
                 const float* __restrict__ bias,
                 const float* __restrict__ wc,
                 const float* __restrict__ C,
                 float* __restrict__ out) {
    __shared__ __align__(16) short Bs[2][16384];  // [buf][lq*4096 + col*8 + off]

    int tid = threadIdx.x;
    int wv = tid >> 6, lane = tid & 63;
    int lm = lane & 15, lq = lane >> 4;
    int m0 = blockIdx.x * 32;

    floatx4 acc[2][4][2];
#pragma unroll
    for (int mt = 0; mt < 2; ++mt)
#pragma unroll
        for (int g = 0; g < 4; ++g)
#pragma unroll
            for (int nt = 0; nt < 2; ++nt) acc[mt][g][nt] = (floatx4)(0.f);

    // stage chunk 0 into buf 0: wave wv copies shorts [wv*4096, wv*4096+4096)
#pragma unroll
    for (int i = 0; i < 8; ++i)
        load_lds16(Wsz + (wv * 8 + i) * 512 + lane * 8, &Bs[0][(wv * 8 + i) * 512]);

    // A prefetch for kb=0 (segment aggX, offset 0 in AGG)
    short8 ca0, ca1;
    {
        const unsigned short* ar = AGG + (size_t)(m0 + lm) * 256 + lq * 8;
        ca0 = *(const short8*)ar;
        ca1 = *(const short8*)(ar + 16 * 256);
    }

    for (int it = 0; it < 16; ++it) {
        __syncthreads();   // drains staging (vmcnt0) + guards buffer reuse
        if (it < 15) {
            const unsigned short* wb = Wsz + (it + 1) * 16384;
            short* lb = Bs[(it + 1) & 1];
#pragma unroll
            for (int i = 0; i < 8; ++i)
                load_lds16(wb + (wv * 8 + i) * 512 + lane * 8, &lb[(wv * 8 + i) * 512]);
        }
        // A prefetch for next iter
        short8 na0, na1;
        if (it < 15) {
            int kn = (it + 1) * 32;
            const unsigned short* ab = (kn & 128) ? XH : AGG;
            int aoff = (kn & 127) | ((kn & 256) >> 1);
            const unsigned short* arn = ab + (size_t)(m0 + lm) * 256 + aoff + lq * 8;
            na0 = *(const short8*)arn;
            na1 = *(const short8*)(arn + 16 * 256);
        }
        // B frags from LDS (conflict-free) + MFMA
        const short* bsc = Bs[it & 1];
#pragma unroll
        for (int g = 0; g < 4; ++g)
#pragma unroll
            for (int nt = 0; nt < 2; ++nt) {
                int col = (g << 7) + (wv << 5) + (nt << 4) + lm;
                short8 b = *(const short8*)&bsc[(lq << 12) + (col << 3)];
                acc[0][g][nt] = __builtin_amdgcn_mfma_f32_16x16x32_bf16(ca0, b, acc[0][g][nt], 0, 0, 0);
                acc[1][g][nt] = __builtin_amdgcn_mfma_f32_16x16x32_bf16(ca1, b, acc[1][g][nt], 0, 0, 0);
            }
        ca0 = na0; ca1 = na1;
    }

    // epilogue: bias/peephole loads here (keeps K-loop register pressure low)
    float bG[4][2], wP[3][2];
#pragma unroll
    for (int nt = 0; nt < 2; ++nt) {
        int cg0 = (wv << 5) + (nt << 4) + lm;
#pragma unroll
        for (int g = 0; g < 4; ++g) bG[g][nt] = bias[(g << 7) + cg0];
#pragma unroll
        for (int j = 0; j < 3; ++j) wP[j][nt] = wc[j * 128 + cg0];
    }

#pragma unroll
    for (int mt = 0; mt < 2; ++mt)
#pragma unroll
        for (int r = 0; r < 4; ++r) {
            int row = m0 + mt * 16 + lq * 4 + r;   // 625*32 == NN exact, no guard
#pragma unroll
            for (int nt = 0; nt < 2; ++nt) {
                int cg0 = (wv << 5) + (nt << 4) + lm;
                float c = C[(size_t)row * D + cg0];
                float pi = acc[mt][0][nt][r] + bG[0][nt] + wP[0][nt] * c;
                float pf = acc[mt][1][nt][r] + bG[1][nt] + wP[1][nt] * c;
                float pt = acc[mt][2][nt][r] + bG[2][nt];
                float po = acc[mt][3][nt][r] + bG[3][nt];
                float I = sigm(pi);
                float F = sigm(pf);
                float T = tanhx(pt);
                float cn = F * c + I * T;
                float O = sigm(po + wP[2][nt] * cn);
                out[(size_t)row * D + cg0] = O * tanhx(cn);
                out[(size_t)NN * D + (size_t)row * D + cg0] = cn;
            }
        }
}

extern "C" void kernel_launch(void* const* d_in, const int* in_sizes, int n_in,
                              void* d_out, int out_size, void* d_ws, size_t ws_size,
                              hipStream_t stream) {
    const float* X  = (const float*)d_in[0];
    const int* ei   = (const int*)d_in[1];
    const float* ew = (const float*)d_in[2];
    const float* H  = (const float*)d_in[3];
    const float* C  = (const float*)d_in[4];
    const float* Wx_l = (const float*)d_in[5];
    const float* Wx_r = (const float*)d_in[6];
    const float* bx   = (const float*)d_in[7];
    const float* Wh_l = (const float*)d_in[8];
    const float* Wh_r = (const float*)d_in[9];
    const float* bh   = (const float*)d_in[10];
    const float* wc   = (const float*)d_in[11];
    const float* bg   = (const float*)d_in[12];
    float* out = (float*)d_out;

    const int* src = ei;
    const int* dst = ei + NE;

    // workspace layout (16B aligned), ~31.3 MB
    char* ws = (char*)d_ws;
    int* cnt = (int*)(ws + 0);                                //     80,000 B
    unsigned int* s_p = (unsigned int*)(ws + 80128);          // 10,240,000 B (20000*128*4)
    unsigned short* XH  = (unsigned short*)(ws + 10320128);   // 10,240,000 B
    unsigned short* AGG = (unsigned short*)(ws + 20560128);   // 10,240,000 B
    unsigned short* Wsz = (unsigned short*)(ws + 30800128);   //    524,288 B
    float* bias = (float*)(ws + 31324416);                    //      2,048 B

    hipMemsetAsync(cnt, 0, NN * sizeof(int), stream);
    prep_fill_kernel<<<640, 256, 0, stream>>>(src, dst, ew, cnt, s_p,
                                              (const float4*)X, (const float4*)H,
                                              (unsigned int*)XH,
                                              Wx_l, Wx_r, Wh_l, Wh_r,
                                              bx, bh, bg, Wsz, bias);
    aggregate_kernel<<<NN / 4, 256, 0, stream>>>((const uint2*)XH, cnt, s_p,
                                                 (uint2*)AGG);
    gemm_lstm_kernel<<<NTILES, 256, 0, stream>>>(XH, AGG, Wsz, bias, wc, C, out);
}